// Round 8
// baseline (353.164 us; speedup 1.0000x reference)
//
#include <hip/hip_runtime.h>
#include <hip/hip_fp16.h>

#define EPS 1e-5f

typedef __attribute__((ext_vector_type(8))) _Float16 half8;
typedef __attribute__((ext_vector_type(4))) float float4v;

// ---------------------------------------------------------------------------
// Generalized batched TN GEMM: C[m][n] = sum_k A[k][m] * B[k][n]
// Offsets per z:  off = (z/div)*bsd + (z%mod)*bsm  (element units)
// KS>1: split-K, atomicAdd into pre-zeroed C. grid.y = Mtiles*KS.
// ---------------------------------------------------------------------------
template<int BM, int BN, int BK, int TM, int TN, int KS, typename TA, typename TC>
__global__ __launch_bounds__((BM/TM)*(BN/TN))
void gemm_tn(const TA* __restrict__ A, const float* __restrict__ B,
             TC* __restrict__ C, int K,
             int lda, int ldb, int ldc,
             int divA, long long bsAd, int modA, long long bsAm,
             int divB, long long bsBd, int modB, long long bsBm,
             int divC, long long bsCd, int modC, long long bsCm)
{
    constexpr int T  = (BM/TM)*(BN/TN);
    constexpr int HM = TM/2, HN = TN/2;
    __shared__ float As[BK][BM];
    __shared__ float Bs[BK][BN];

    const int tid = threadIdx.x;
    const int z = blockIdx.z;
    const int mtile = blockIdx.y / KS;
    const int ks = blockIdx.y % KS;
    const int n0 = blockIdx.x * BN;
    const int m0 = mtile * BM;
    A += (long long)(z / divA) * bsAd + (long long)(z % modA) * bsAm;
    B += (long long)(z / divB) * bsBd + (long long)(z % modB) * bsBm;
    C += (long long)(z / divC) * bsCd + (long long)(z % modC) * bsCm;

    const int tx = tid % (BN/TN);
    const int ty = tid / (BN/TN);

    float acc[TM][TN] = {};

    const int kc = K / KS;
    const int kBeg = ks * kc;

    for (int k0 = kBeg; k0 < kBeg + kc; k0 += BK) {
#pragma unroll
        for (int idx = tid * 4; idx < BK * BM; idx += T * 4) {
            int rr = idx / BM, cc = idx % BM;
            *(float4*)&As[rr][cc] = *(const float4*)(A + (long long)(k0 + rr) * lda + m0 + cc);
        }
#pragma unroll
        for (int idx = tid * 4; idx < BK * BN; idx += T * 4) {
            int rr = idx / BN, cc = idx % BN;
            *(float4*)&Bs[rr][cc] = *(const float4*)(B + (long long)(k0 + rr) * ldb + n0 + cc);
        }
        __syncthreads();
#pragma unroll
        for (int kk = 0; kk < BK; kk++) {
            float a[TM], b[TN];
#pragma unroll
            for (int u = 0; u < HM; u++) {
                a[u]      = As[kk][ty * HM + u];
                a[HM + u] = As[kk][BM / 2 + ty * HM + u];
            }
#pragma unroll
            for (int v = 0; v < HN; v++) {
                b[v]      = Bs[kk][tx * HN + v];
                b[HN + v] = Bs[kk][BN / 2 + tx * HN + v];
            }
#pragma unroll
            for (int u = 0; u < TM; u++)
#pragma unroll
                for (int v = 0; v < TN; v++)
                    acc[u][v] += a[u] * b[v];
        }
        __syncthreads();
    }

    if constexpr (KS > 1) {
#pragma unroll
        for (int u = 0; u < TM; u++) {
            int rl = (u < HM) ? ty * HM + u : BM / 2 + ty * HM + (u - HM);
#pragma unroll
            for (int v = 0; v < TN; v++) {
                int cl = (v < HN) ? tx * HN + v : BN / 2 + tx * HN + (v - HN);
                atomicAdd(&C[(long long)(m0 + rl) * ldc + n0 + cl], acc[u][v]);
            }
        }
    } else {
#pragma unroll
        for (int u = 0; u < TM; u++) {
            int rl = (u < HM) ? ty * HM + u : BM / 2 + ty * HM + (u - HM);
            TC* cr = C + (long long)(m0 + rl) * ldc + n0;
            if constexpr (sizeof(TC) == 2) {
#pragma unroll
                for (int v = 0; v < HN; v++) {
                    cr[tx * HN + v]          = __float2half(acc[u][v]);
                    cr[BN / 2 + tx * HN + v] = __float2half(acc[u][HN + v]);
                }
            } else if constexpr (HN == 4) {
                *(float4*)(cr + tx * HN) = make_float4(acc[u][0], acc[u][1], acc[u][2], acc[u][3]);
                *(float4*)(cr + BN / 2 + tx * HN) = make_float4(acc[u][4], acc[u][5], acc[u][6], acc[u][7]);
            } else {
#pragma unroll
                for (int v = 0; v < HN; v++) {
                    cr[tx * HN + v] = acc[u][v];
                    cr[BN / 2 + tx * HN + v] = acc[u][HN + v];
                }
            }
        }
    }
}

// ---------------------------------------------------------------------------
// MFMA rowsums:  rs[db][i] += sum_ch exp(r * S[i][ch-tile])  (no S store).
// E16: [pair z][512 i][64 c'] fp16; WkT16: [512 ch][64 c'] fp16.
// r computed inline from sums. grid (4 ch-tiles, 4 i-tiles, 128 pairs).
// ---------------------------------------------------------------------------
__global__ __launch_bounds__(256)
void mfma_rows(const __half* __restrict__ E16, const __half* __restrict__ WkT16,
               const float* __restrict__ sums, float* __restrict__ rs)
{
    __shared__ __half Es[128][72];
    __shared__ __half Ws[128][72];
    const int tid = threadIdx.x;
    const int z = blockIdx.z;          // pair = db*8 + b'
    const int i0 = blockIdx.y * 128;
    const int ch0 = blockIdx.x * 128;
    const int db = z >> 3;
    const __half* Ez = E16 + (long long)z * 32768;

#pragma unroll
    for (int it = 0; it < 4; it++) {
        int e = tid + it * 256;
        int row = e >> 3, c8 = (e & 7) * 8;
        *(half8*)&Es[row][c8] = *(const half8*)(Ez + (long long)(i0 + row) * 64 + c8);
        *(half8*)&Ws[row][c8] = *(const half8*)(WkT16 + (long long)(ch0 + row) * 64 + c8);
    }
    __syncthreads();

    const int lane = tid & 63;
    const int w = tid >> 6;
    const int q = lane >> 4;
    const int l16 = lane & 15;

    float4v acc[2][8];
#pragma unroll
    for (int a = 0; a < 2; a++)
#pragma unroll
        for (int b = 0; b < 8; b++) acc[a][b] = (float4v)0.f;

#pragma unroll
    for (int kc = 0; kc < 64; kc += 32) {
        half8 af[2], bf[8];
#pragma unroll
        for (int mt = 0; mt < 2; mt++)
            af[mt] = *(const half8*)&Es[w * 32 + mt * 16 + l16][kc + q * 8];
#pragma unroll
        for (int nt = 0; nt < 8; nt++)
            bf[nt] = *(const half8*)&Ws[nt * 16 + l16][kc + q * 8];
#pragma unroll
        for (int mt = 0; mt < 2; mt++)
#pragma unroll
            for (int nt = 0; nt < 8; nt++)
                acc[mt][nt] = __builtin_amdgcn_mfma_f32_16x16x32_f16(af[mt], bf[nt], acc[mt][nt], 0, 0, 0);
    }

    const float inv = 1.f / 2097152.f;
    const float mu  = sums[2 * db] * inv;
    const float var = sums[2 * db + 1] * inv - mu * mu;
    const float rv  = rsqrtf(var + EPS);

    float* rsb = rs + db * 512 + i0 + w * 32;
#pragma unroll
    for (int mt = 0; mt < 2; mt++) {
#pragma unroll
        for (int t = 0; t < 4; t++) {
            const int irow = mt * 16 + q * 4 + t;
            float p = 0.f;
#pragma unroll
            for (int nt = 0; nt < 8; nt++) p += __expf(rv * acc[mt][nt][t]);
            p += __shfl_xor(p, 1, 16);
            p += __shfl_xor(p, 2, 16);
            p += __shfl_xor(p, 4, 16);
            p += __shfl_xor(p, 8, 16);
            if (l16 == 0) atomicAdd(&rsb[irow], p);
        }
    }
}

// ---------------------------------------------------------------------------
// Fused S-recompute + exp + U2 contraction (expS never hits HBM):
//   per (db, j-tile of 128 where j = b'*512+ch):
//     loop i-chunks of 64:
//       St[ch][i] = Ws(ch rows) x Es(i rows) MFMA      (A=[m][k], B=[n][k])
//       P = fp16(exp(rv*St)) -> LDS Pt[i][ch] (XOR-swizzled)
//       U2acc[ch][o] += Pt^T x Wos  (A=Pt [k][m] col-reads, B=Wos [n][k])
//   U2[db][j][o] = U2acc/4096   (Wo16T pre-scaled by 4096/rs)
// grid (32 jt, 16 db), block 256 (4 waves). LDS ~53 KB.
// ---------------------------------------------------------------------------
__global__ __launch_bounds__(256)
void mfma_su2(const __half* __restrict__ E16, const __half* __restrict__ WkT16,
              const __half* __restrict__ Wo16T, const float* __restrict__ sums,
              float* __restrict__ U2)
{
    __shared__ __half Ws[128][72];
    __shared__ __half Es[64][72];
    __shared__ __half Wos[64][72];
    __shared__ __half Pt[64][136];

    const int tid = threadIdx.x;
    const int jt = blockIdx.x;
    const int db = blockIdx.y;
    const int bp = jt >> 2;
    const int ch0 = (jt & 3) * 128;
    const int z = db * 8 + bp;

    const __half* Ez = E16 + (long long)z * 32768;
    const __half* Woz = Wo16T + (long long)db * 32768;

#pragma unroll
    for (int it = 0; it < 4; it++) {
        int e = tid + it * 256;
        int row = e >> 3, c8 = (e & 7) * 8;
        *(half8*)&Ws[row][c8] = *(const half8*)(WkT16 + (long long)(ch0 + row) * 64 + c8);
    }

    const int lane = tid & 63;
    const int w = tid >> 6;
    const int q = lane >> 4;
    const int l16 = lane & 15;

    const float inv = 1.f / 2097152.f;
    const float mu  = sums[2 * db] * inv;
    const float var = sums[2 * db + 1] * inv - mu * mu;
    const float rv  = rsqrtf(var + EPS);

    float4v u2acc[2][4];
#pragma unroll
    for (int a = 0; a < 2; a++)
#pragma unroll
        for (int b = 0; b < 4; b++) u2acc[a][b] = (float4v)0.f;

    const int lrow = tid >> 2;         // 0..63
    const int lc8 = (tid & 3) * 16;    // 0,16,32,48

    for (int i0 = 0; i0 < 512; i0 += 64) {
        *(half8*)&Es[lrow][lc8]      = *(const half8*)(Ez + (long long)(i0 + lrow) * 64 + lc8);
        *(half8*)&Es[lrow][lc8 + 8]  = *(const half8*)(Ez + (long long)(i0 + lrow) * 64 + lc8 + 8);
        *(half8*)&Wos[lrow][lc8]     = *(const half8*)(Woz + (long long)lrow * 512 + i0 + lc8);
        *(half8*)&Wos[lrow][lc8 + 8] = *(const half8*)(Woz + (long long)lrow * 512 + i0 + lc8 + 8);
        __syncthreads();

        // St[ch][i]: wave w -> ch rows w*32..+31 (2 m-tiles), 4 i n-tiles
        float4v sacc[2][4];
#pragma unroll
        for (int a = 0; a < 2; a++)
#pragma unroll
            for (int b = 0; b < 4; b++) sacc[a][b] = (float4v)0.f;
#pragma unroll
        for (int kc = 0; kc < 64; kc += 32) {
            half8 af[2], bf[4];
#pragma unroll
            for (int ct = 0; ct < 2; ct++)
                af[ct] = *(const half8*)&Ws[w * 32 + ct * 16 + l16][kc + q * 8];
#pragma unroll
            for (int it = 0; it < 4; it++)
                bf[it] = *(const half8*)&Es[it * 16 + l16][kc + q * 8];
#pragma unroll
            for (int ct = 0; ct < 2; ct++)
#pragma unroll
                for (int it = 0; it < 4; it++)
                    sacc[ct][it] = __builtin_amdgcn_mfma_f32_16x16x32_f16(af[ct], bf[it], sacc[ct][it], 0, 0, 0);
        }

        // exp + transpose into Pt[i][ch ^ swz]
#pragma unroll
        for (int ct = 0; ct < 2; ct++)
#pragma unroll
            for (int it = 0; it < 4; it++) {
                float e0 = __expf(rv * sacc[ct][it][0]);
                float e1 = __expf(rv * sacc[ct][it][1]);
                float e2 = __expf(rv * sacc[ct][it][2]);
                float e3 = __expf(rv * sacc[ct][it][3]);
                int row = it * 16 + l16;                         // i local
                int swz = ((row >> 3) & 3) << 4;
                int col = (w * 32 + ct * 16 + q * 4) ^ swz;      // ch local
                *(__half2*)&Pt[row][col]     = __floats2half2_rn(e0, e1);
                *(__half2*)&Pt[row][col + 2] = __floats2half2_rn(e2, e3);
            }
        __syncthreads();

        // U2 += Pt^T x Wos : A[m=ch][k=i] via swizzled column reads
#pragma unroll
        for (int kc = 0; kc < 64; kc += 32) {
            half8 af2[2], bf2[4];
#pragma unroll
            for (int mt = 0; mt < 2; mt++) {
                const int cph = (w * 32 + mt * 16 + l16) ^ (q << 4);
#pragma unroll
                for (int t = 0; t < 8; t++)
                    af2[mt][t] = Pt[kc + q * 8 + t][cph];
            }
#pragma unroll
            for (int ot = 0; ot < 4; ot++)
                bf2[ot] = *(const half8*)&Wos[ot * 16 + l16][kc + q * 8];
#pragma unroll
            for (int mt = 0; mt < 2; mt++)
#pragma unroll
                for (int ot = 0; ot < 4; ot++)
                    u2acc[mt][ot] = __builtin_amdgcn_mfma_f32_16x16x32_f16(af2[mt], bf2[ot], u2acc[mt][ot], 0, 0, 0);
        }
        __syncthreads();
    }

    const float sc = 1.f / 4096.f;
    float* Ud = U2 + (long long)db * 262144;
#pragma unroll
    for (int mt = 0; mt < 2; mt++)
#pragma unroll
        for (int ot = 0; ot < 4; ot++)
#pragma unroll
            for (int t = 0; t < 4; t++) {
                int j = bp * 512 + ch0 + w * 32 + mt * 16 + q * 4 + t;
                Ud[(long long)j * 64 + ot * 16 + l16] = u2acc[mt][ot][t] * sc;
            }
}

// ---------------------------------------------------------------------------
// Wo16T[z][o][i] = fp16(Wo[i][o] * 4096 / rs[z][i]).  grid 16, block 256.
// ---------------------------------------------------------------------------
__global__ __launch_bounds__(256)
void woprep_k(const float* __restrict__ Wo, const float* __restrict__ rs,
              __half* __restrict__ Wo16T)
{
    const int z = blockIdx.x;
    for (int idx = threadIdx.x; idx < 32768; idx += 256) {
        int o = idx >> 9, i = idx & 511;
        float v = Wo[i * 64 + o] * 4096.0f / rs[z * 512 + i];
        Wo16T[z * 32768 + idx] = __float2half(v);
    }
}

// ---------------------------------------------------------------------------
// 64x64 LDS tile transpose (emb)
// ---------------------------------------------------------------------------
__global__ __launch_bounds__(256)
void transpose_k(const float* __restrict__ in, float* __restrict__ out,
                 int rows, int cols, int ldin, int ldout,
                 long long bsIn, long long bsOut)
{
    __shared__ float t[64][65];
    in += blockIdx.z * bsIn;
    out += blockIdx.z * bsOut;
    const int c0 = blockIdx.x * 64, r0 = blockIdx.y * 64;
    const int c = threadIdx.x & 63, r4 = threadIdx.x >> 6;
#pragma unroll
    for (int rr = r4; rr < 64; rr += 4)
        t[rr][c] = in[(long long)(r0 + rr) * ldin + c0 + c];
    __syncthreads();
#pragma unroll
    for (int rr = r4; rr < 64; rr += 4)
        out[(long long)(c0 + rr) * ldout + r0 + c] = t[c][rr];
}

// ---------------------------------------------------------------------------
// Weight prep: transpose Wq/Wk/Wv (64x512 -> 512x64); also fp16 copy of WkT.
// grid (8, 3), block 256.
// ---------------------------------------------------------------------------
__global__ __launch_bounds__(256)
void wprep_k(const float* __restrict__ Wq, const float* __restrict__ Wk,
             const float* __restrict__ Wv, float* __restrict__ WqT,
             float* __restrict__ WkT, float* __restrict__ WvT,
             __half* __restrict__ WkT16)
{
    const int which = blockIdx.y;
    const float* in = which == 0 ? Wq : (which == 1 ? Wk : Wv);
    float* out      = which == 0 ? WqT : (which == 1 ? WkT : WvT);
    __shared__ float t[64][65];
    const int c0 = blockIdx.x * 64;
    const int c = threadIdx.x & 63, r4 = threadIdx.x >> 6;
#pragma unroll
    for (int rr = r4; rr < 64; rr += 4)
        t[rr][c] = in[rr * 512 + c0 + c];
    __syncthreads();
#pragma unroll
    for (int rr = r4; rr < 64; rr += 4) {
        float v = t[c][rr];
        out[(c0 + rr) * 64 + c] = v;
        if (which == 1) WkT16[(c0 + rr) * 64 + c] = __float2half(v);
    }
}

// ---------------------------------------------------------------------------
// Row sums of the 64x512 weight matrices.
// ---------------------------------------------------------------------------
__global__ __launch_bounds__(256)
void wsum_k(const float* __restrict__ Wq, const float* __restrict__ Wk,
            float* __restrict__ wqs, float* __restrict__ wks)
{
    const float* W = blockIdx.x ? Wk : Wq;
    float* o = blockIdx.x ? wks : wqs;
    __shared__ float acc[64];
    if (threadIdx.x < 64) acc[threadIdx.x] = 0.f;
    __syncthreads();
    for (int idx = threadIdx.x * 4; idx < 32768; idx += 1024) {
        float4 v = *(const float4*)(W + idx);
        atomicAdd(&acc[idx >> 9], v.x + v.y + v.z + v.w);
    }
    __syncthreads();
    if (threadIdx.x < 64) o[threadIdx.x] = acc[threadIdx.x];
}

// ---------------------------------------------------------------------------
// Analytic InstanceNorm stats from 64x64 Grams:
//   s1_pair = wqs^T G_pair wks ; s2_pair = <GQ*G_pair, G_pair*GW>
// ---------------------------------------------------------------------------
__global__ __launch_bounds__(256)
void stats2_k(const float* __restrict__ G, const float* __restrict__ GQ,
              const float* __restrict__ GW, const float* __restrict__ wqs,
              const float* __restrict__ wks, float* __restrict__ sums)
{
    __shared__ float Gs[64][68], GQs[64][68], GWs[64][68];
    const int tid = threadIdx.x;
    const float* Gp = G + (long long)blockIdx.x * 4096;
    for (int f = tid * 4; f < 4096; f += 1024) {
        int rr = f >> 6, cc = f & 63;
        *(float4*)&Gs[rr][cc]  = *(const float4*)(Gp + f);
        *(float4*)&GQs[rr][cc] = *(const float4*)(GQ + f);
        *(float4*)&GWs[rr][cc] = *(const float4*)(GW + f);
    }
    __syncthreads();
    const int r = tid >> 2;
    const int c0 = (tid & 3) * 16;
    float p1[16] = {}, p2[16] = {};
    for (int k = 0; k < 64; k++) {
        float gq = GQs[r][k], g = Gs[r][k];
#pragma unroll
        for (int j = 0; j < 16; j++) {
            p1[j] += gq * Gs[k][c0 + j];
            p2[j] += g  * GWs[k][c0 + j];
        }
    }
    float s2 = 0.f;
#pragma unroll
    for (int j = 0; j < 16; j++) s2 += p1[j] * p2[j];
    float s1 = 0.f;
    const float wq = wqs[r];
#pragma unroll
    for (int j = 0; j < 16; j++) s1 += wq * Gs[r][c0 + j] * wks[c0 + j];

    const int lane = tid & 63, w = tid >> 6;
#pragma unroll
    for (int off = 32; off; off >>= 1) {
        s1 += __shfl_down(s1, off, 64);
        s2 += __shfl_down(s2, off, 64);
    }
    __shared__ float r1[4], r2[4];
    if (lane == 0) { r1[w] = s1; r2[w] = s2; }
    __syncthreads();
    if (tid == 0) {
        atomicAdd(&sums[(blockIdx.x >> 3) * 2],     r1[0] + r1[1] + r1[2] + r1[3]);
        atomicAdd(&sums[(blockIdx.x >> 3) * 2 + 1], r2[0] + r2[1] + r2[2] + r2[3]);
    }
}

// ---------------------------------------------------------------------------
// Workspace (float offsets):
//   XT2 @0:2097152 | WkT @2097152 | WqT @2129920 | WvT @2162688
//   zeroed block: G @2195456:524288 | rs @2719744:8192 | sums @2727936:32
//                 GW @2727968:4096 | GQ @2732064:4096   (memset 540704)
//   wqs @2736160:64 | wks @2736224:64
//   E16 (half) @2736288: 4194304 halves -> ends 4833440
//   Wo16T (half) @4833440: 524288 halves -> ends 5095584
//   WkT16 (half) @5095584: 32768 halves -> ends 5111968
//   U2 @5111968: 4194304 floats | Zst @9306272: 524288 [zeroed]
// ---------------------------------------------------------------------------
extern "C" void kernel_launch(void* const* d_in, const int* in_sizes, int n_in,
                              void* d_out, int out_size, void* d_ws, size_t ws_size,
                              hipStream_t stream)
{
    const float* emb = (const float*)d_in[0];
    const float* Wq  = (const float*)d_in[1];
    const float* Wk  = (const float*)d_in[2];
    const float* Wv  = (const float*)d_in[3];
    const float* Wo  = (const float*)d_in[4];
    float* out = (float*)d_out;
    float* ws  = (float*)d_ws;

    float* XT2   = ws;
    float* WkT   = ws + 2097152;
    float* WqT   = ws + 2129920;
    float* WvT   = ws + 2162688;
    float* G     = ws + 2195456;
    float* rs    = ws + 2719744;
    float* sums  = ws + 2727936;
    float* GW    = ws + 2727968;
    float* GQ    = ws + 2732064;
    float* wqs   = ws + 2736160;
    float* wks   = ws + 2736224;
    __half* E16   = (__half*)(ws + 2736288);
    __half* Wo16T = (__half*)(ws + 4833440);
    __half* WkT16 = (__half*)(ws + 5095584);
    float* U2    = ws + 5111968;
    float* Zst   = ws + 9306272;

    transpose_k<<<dim3(1, 32, 16), 256, 0, stream>>>(emb, XT2, 2048, 64, 64, 2048, 131072LL, 131072LL);
    wprep_k<<<dim3(8, 3), 256, 0, stream>>>(Wq, Wk, Wv, WqT, WkT, WvT, WkT16);
    hipMemsetAsync(G, 0, 540704 * sizeof(float), stream);     // G+rs+sums+GW+GQ
    hipMemsetAsync(Zst, 0, 524288 * sizeof(float), stream);
    hipMemsetAsync(out, 0, (size_t)out_size * sizeof(float), stream);
    wsum_k<<<2, 256, 0, stream>>>(Wq, Wk, wqs, wks);

    // G[z=(d*8+b)*8+b'] = emb_q[d,b]^T @ emb_kv[d,b']   K=2048 split-K16
    gemm_tn<64, 64, 16, 4, 4, 16, float, float><<<dim3(1, 16, 128), 256, 0, stream>>>(
        emb, emb + 1048576, G, 2048, 64, 64, 64,
        8, 131072LL, 1, 0LL,
        64, -1048576LL, 8, 131072LL,
        1, 4096LL, 1, 0LL);

    // GW (z=0 from WkT) and GQ (z=1 from WqT): 64x64, K=512, split-K8 batched
    gemm_tn<64, 64, 16, 4, 4, 8, float, float><<<dim3(1, 8, 2), 256, 0, stream>>>(
        WkT, WkT, GW, 512, 64, 64, 64,
        1, 0LL, 2, 32768LL,
        1, 0LL, 2, 32768LL,
        1, 0LL, 2, 4096LL);

    stats2_k<<<128, 256, 0, stream>>>(G, GQ, GW, wqs, wks, sums);

    // E16[pair][i][c'] = sum_c Wq[c][i] * G[pair][c][c']   (fp16 out)
    gemm_tn<64, 64, 16, 4, 4, 1, float, __half><<<dim3(1, 8, 128), 256, 0, stream>>>(
        Wq, G, E16, 64, 512, 64, 64,
        1, 0LL, 1, 0LL,
        1, 4096LL, 1, 0LL,
        1, 32768LL, 1, 0LL);

    // rs[db][i] = sum_j exp(r * S[i][j])   (MFMA, no S store)
    mfma_rows<<<dim3(4, 4, 128), 256, 0, stream>>>(E16, WkT16, sums, rs);

    // Wo16T[db][o][i] = fp16(Wo[i][o]*4096/rs[db][i])
    woprep_k<<<16, 256, 0, stream>>>(Wo, rs, Wo16T);

    // U2[db][j][o] = (1/4096) sum_i exp(r*S[i][j]) * Wo16T[o][i]  (fused)
    mfma_su2<<<dim3(32, 16), 256, 0, stream>>>(E16, WkT16, Wo16T, sums, U2);

    // Z[d,b,b'][c][o] = sum_ch WvT[ch][c] * U2[b'*512+ch][o]   split-K4
    gemm_tn<64, 64, 16, 4, 4, 4, float, float><<<dim3(1, 4, 128), 256, 0, stream>>>(
        WvT, U2, Zst, 512, 64, 64, 64,
        1, 0LL, 1, 0LL,
        8, 262144LL, 8, 32768LL,
        1, 4096LL, 1, 0LL);

    // out[d*8+b][n][c] = sum_{b',c} XT2_kv[b'*64+c][n] * Zst[b'*64+c][o]  split-K4
    gemm_tn<64, 64, 16, 4, 4, 4, float, float><<<dim3(1, 128, 16), 256, 0, stream>>>(
        XT2 + 1048576, Zst, out, 512, 2048, 64, 64,
        8, -1048576LL, 1, 0LL,
        1, 32768LL, 1, 0LL,
        1, 131072LL, 1, 0LL);
}

// Round 9
// 305.576 us; speedup vs baseline: 1.1557x; 1.1557x over previous
//
#include <hip/hip_runtime.h>
#include <hip/hip_fp16.h>

#define EPS 1e-5f

typedef __attribute__((ext_vector_type(8))) _Float16 half8;
typedef __attribute__((ext_vector_type(4))) float float4v;

// ---------------------------------------------------------------------------
// Generalized batched TN GEMM: C[m][n] = sum_k A[k][m] * B[k][n]
// Offsets per z:  off = (z/div)*bsd + (z%mod)*bsm  (element units)
// KS>1: split-K, atomicAdd into pre-zeroed C. grid.y = Mtiles*KS.
// TC=__half: scalar converting stores (full overwrite, KS==1 only).
// ---------------------------------------------------------------------------
template<int BM, int BN, int BK, int TM, int TN, int KS, typename TA, typename TC>
__global__ __launch_bounds__((BM/TM)*(BN/TN))
void gemm_tn(const TA* __restrict__ A, const float* __restrict__ B,
             TC* __restrict__ C, int K,
             int lda, int ldb, int ldc,
             int divA, long long bsAd, int modA, long long bsAm,
             int divB, long long bsBd, int modB, long long bsBm,
             int divC, long long bsCd, int modC, long long bsCm)
{
    constexpr int T  = (BM/TM)*(BN/TN);
    constexpr int HM = TM/2, HN = TN/2;
    __shared__ float As[BK][BM];
    __shared__ float Bs[BK][BN];

    const int tid = threadIdx.x;
    const int z = blockIdx.z;
    const int mtile = blockIdx.y / KS;
    const int ks = blockIdx.y % KS;
    const int n0 = blockIdx.x * BN;
    const int m0 = mtile * BM;
    A += (long long)(z / divA) * bsAd + (long long)(z % modA) * bsAm;
    B += (long long)(z / divB) * bsBd + (long long)(z % modB) * bsBm;
    C += (long long)(z / divC) * bsCd + (long long)(z % modC) * bsCm;

    const int tx = tid % (BN/TN);
    const int ty = tid / (BN/TN);

    float acc[TM][TN] = {};

    const int kc = K / KS;
    const int kBeg = ks * kc;

    for (int k0 = kBeg; k0 < kBeg + kc; k0 += BK) {
#pragma unroll
        for (int idx = tid * 4; idx < BK * BM; idx += T * 4) {
            int rr = idx / BM, cc = idx % BM;
            *(float4*)&As[rr][cc] = *(const float4*)(A + (long long)(k0 + rr) * lda + m0 + cc);
        }
#pragma unroll
        for (int idx = tid * 4; idx < BK * BN; idx += T * 4) {
            int rr = idx / BN, cc = idx % BN;
            *(float4*)&Bs[rr][cc] = *(const float4*)(B + (long long)(k0 + rr) * ldb + n0 + cc);
        }
        __syncthreads();
#pragma unroll
        for (int kk = 0; kk < BK; kk++) {
            float a[TM], b[TN];
#pragma unroll
            for (int u = 0; u < HM; u++) {
                a[u]      = As[kk][ty * HM + u];
                a[HM + u] = As[kk][BM / 2 + ty * HM + u];
            }
#pragma unroll
            for (int v = 0; v < HN; v++) {
                b[v]      = Bs[kk][tx * HN + v];
                b[HN + v] = Bs[kk][BN / 2 + tx * HN + v];
            }
#pragma unroll
            for (int u = 0; u < TM; u++)
#pragma unroll
                for (int v = 0; v < TN; v++)
                    acc[u][v] += a[u] * b[v];
        }
        __syncthreads();
    }

    if constexpr (KS > 1) {
#pragma unroll
        for (int u = 0; u < TM; u++) {
            int rl = (u < HM) ? ty * HM + u : BM / 2 + ty * HM + (u - HM);
#pragma unroll
            for (int v = 0; v < TN; v++) {
                int cl = (v < HN) ? tx * HN + v : BN / 2 + tx * HN + (v - HN);
                atomicAdd(&C[(long long)(m0 + rl) * ldc + n0 + cl], acc[u][v]);
            }
        }
    } else {
#pragma unroll
        for (int u = 0; u < TM; u++) {
            int rl = (u < HM) ? ty * HM + u : BM / 2 + ty * HM + (u - HM);
            TC* cr = C + (long long)(m0 + rl) * ldc + n0;
            if constexpr (sizeof(TC) == 2) {
#pragma unroll
                for (int v = 0; v < HN; v++) {
                    cr[tx * HN + v]          = __float2half(acc[u][v]);
                    cr[BN / 2 + tx * HN + v] = __float2half(acc[u][HN + v]);
                }
            } else if constexpr (HN == 4) {
                *(float4*)(cr + tx * HN) = make_float4(acc[u][0], acc[u][1], acc[u][2], acc[u][3]);
                *(float4*)(cr + BN / 2 + tx * HN) = make_float4(acc[u][4], acc[u][5], acc[u][6], acc[u][7]);
            } else {
#pragma unroll
                for (int v = 0; v < HN; v++) {
                    cr[tx * HN + v] = acc[u][v];
                    cr[BN / 2 + tx * HN + v] = acc[u][HN + v];
                }
            }
        }
    }
}

// ---------------------------------------------------------------------------
// MFMA rowsums:  rs[db][i] += sum_ch exp(r * S[i][ch-tile])  (no S store).
// ---------------------------------------------------------------------------
__global__ __launch_bounds__(256)
void mfma_rows(const __half* __restrict__ E16, const __half* __restrict__ WkT16,
               const float* __restrict__ sums, float* __restrict__ rs)
{
    __shared__ __half Es[128][72];
    __shared__ __half Ws[128][72];
    const int tid = threadIdx.x;
    const int z = blockIdx.z;          // pair = db*8 + b'
    const int i0 = blockIdx.y * 128;
    const int ch0 = blockIdx.x * 128;
    const int db = z >> 3;
    const __half* Ez = E16 + (long long)z * 32768;

#pragma unroll
    for (int it = 0; it < 4; it++) {
        int e = tid + it * 256;
        int row = e >> 3, c8 = (e & 7) * 8;
        *(half8*)&Es[row][c8] = *(const half8*)(Ez + (long long)(i0 + row) * 64 + c8);
        *(half8*)&Ws[row][c8] = *(const half8*)(WkT16 + (long long)(ch0 + row) * 64 + c8);
    }
    __syncthreads();

    const int lane = tid & 63;
    const int w = tid >> 6;
    const int q = lane >> 4;
    const int l16 = lane & 15;

    float4v acc[2][8];
#pragma unroll
    for (int a = 0; a < 2; a++)
#pragma unroll
        for (int b = 0; b < 8; b++) acc[a][b] = (float4v)0.f;

#pragma unroll
    for (int kc = 0; kc < 64; kc += 32) {
        half8 af[2], bf[8];
#pragma unroll
        for (int mt = 0; mt < 2; mt++)
            af[mt] = *(const half8*)&Es[w * 32 + mt * 16 + l16][kc + q * 8];
#pragma unroll
        for (int nt = 0; nt < 8; nt++)
            bf[nt] = *(const half8*)&Ws[nt * 16 + l16][kc + q * 8];
#pragma unroll
        for (int mt = 0; mt < 2; mt++)
#pragma unroll
            for (int nt = 0; nt < 8; nt++)
                acc[mt][nt] = __builtin_amdgcn_mfma_f32_16x16x32_f16(af[mt], bf[nt], acc[mt][nt], 0, 0, 0);
    }

    const float inv = 1.f / 2097152.f;
    const float mu  = sums[2 * db] * inv;
    const float var = sums[2 * db + 1] * inv - mu * mu;
    const float rv  = rsqrtf(var + EPS);

    float* rsb = rs + db * 512 + i0 + w * 32;
#pragma unroll
    for (int mt = 0; mt < 2; mt++) {
#pragma unroll
        for (int t = 0; t < 4; t++) {
            const int irow = mt * 16 + q * 4 + t;
            float p = 0.f;
#pragma unroll
            for (int nt = 0; nt < 8; nt++) p += __expf(rv * acc[mt][nt][t]);
            p += __shfl_xor(p, 1, 16);
            p += __shfl_xor(p, 2, 16);
            p += __shfl_xor(p, 4, 16);
            p += __shfl_xor(p, 8, 16);
            if (l16 == 0) atomicAdd(&rsb[irow], p);
        }
    }
}

// ---------------------------------------------------------------------------
// Fused S-recompute + exp + U2 contraction (expS never hits HBM).
// ---------------------------------------------------------------------------
__global__ __launch_bounds__(256)
void mfma_su2(const __half* __restrict__ E16, const __half* __restrict__ WkT16,
              const __half* __restrict__ Wo16T, const float* __restrict__ sums,
              float* __restrict__ U2)
{
    __shared__ __half Ws[128][72];
    __shared__ __half Es[64][72];
    __shared__ __half Wos[64][72];
    __shared__ __half Pt[64][136];

    const int tid = threadIdx.x;
    const int jt = blockIdx.x;
    const int db = blockIdx.y;
    const int bp = jt >> 2;
    const int ch0 = (jt & 3) * 128;
    const int z = db * 8 + bp;

    const __half* Ez = E16 + (long long)z * 32768;
    const __half* Woz = Wo16T + (long long)db * 32768;

#pragma unroll
    for (int it = 0; it < 4; it++) {
        int e = tid + it * 256;
        int row = e >> 3, c8 = (e & 7) * 8;
        *(half8*)&Ws[row][c8] = *(const half8*)(WkT16 + (long long)(ch0 + row) * 64 + c8);
    }

    const int lane = tid & 63;
    const int w = tid >> 6;
    const int q = lane >> 4;
    const int l16 = lane & 15;

    const float inv = 1.f / 2097152.f;
    const float mu  = sums[2 * db] * inv;
    const float var = sums[2 * db + 1] * inv - mu * mu;
    const float rv  = rsqrtf(var + EPS);

    float4v u2acc[2][4];
#pragma unroll
    for (int a = 0; a < 2; a++)
#pragma unroll
        for (int b = 0; b < 4; b++) u2acc[a][b] = (float4v)0.f;

    const int lrow = tid >> 2;         // 0..63
    const int lc8 = (tid & 3) * 16;    // 0,16,32,48

    for (int i0 = 0; i0 < 512; i0 += 64) {
        *(half8*)&Es[lrow][lc8]      = *(const half8*)(Ez + (long long)(i0 + lrow) * 64 + lc8);
        *(half8*)&Es[lrow][lc8 + 8]  = *(const half8*)(Ez + (long long)(i0 + lrow) * 64 + lc8 + 8);
        *(half8*)&Wos[lrow][lc8]     = *(const half8*)(Woz + (long long)lrow * 512 + i0 + lc8);
        *(half8*)&Wos[lrow][lc8 + 8] = *(const half8*)(Woz + (long long)lrow * 512 + i0 + lc8 + 8);
        __syncthreads();

        float4v sacc[2][4];
#pragma unroll
        for (int a = 0; a < 2; a++)
#pragma unroll
            for (int b = 0; b < 4; b++) sacc[a][b] = (float4v)0.f;
#pragma unroll
        for (int kc = 0; kc < 64; kc += 32) {
            half8 af[2], bf[4];
#pragma unroll
            for (int ct = 0; ct < 2; ct++)
                af[ct] = *(const half8*)&Ws[w * 32 + ct * 16 + l16][kc + q * 8];
#pragma unroll
            for (int it = 0; it < 4; it++)
                bf[it] = *(const half8*)&Es[it * 16 + l16][kc + q * 8];
#pragma unroll
            for (int ct = 0; ct < 2; ct++)
#pragma unroll
                for (int it = 0; it < 4; it++)
                    sacc[ct][it] = __builtin_amdgcn_mfma_f32_16x16x32_f16(af[ct], bf[it], sacc[ct][it], 0, 0, 0);
        }

#pragma unroll
        for (int ct = 0; ct < 2; ct++)
#pragma unroll
            for (int it = 0; it < 4; it++) {
                float e0 = __expf(rv * sacc[ct][it][0]);
                float e1 = __expf(rv * sacc[ct][it][1]);
                float e2 = __expf(rv * sacc[ct][it][2]);
                float e3 = __expf(rv * sacc[ct][it][3]);
                int row = it * 16 + l16;
                int swz = ((row >> 3) & 3) << 4;
                int col = (w * 32 + ct * 16 + q * 4) ^ swz;
                *(__half2*)&Pt[row][col]     = __floats2half2_rn(e0, e1);
                *(__half2*)&Pt[row][col + 2] = __floats2half2_rn(e2, e3);
            }
        __syncthreads();

#pragma unroll
        for (int kc = 0; kc < 64; kc += 32) {
            half8 af2[2], bf2[4];
#pragma unroll
            for (int mt = 0; mt < 2; mt++) {
                const int cph = (w * 32 + mt * 16 + l16) ^ (q << 4);
#pragma unroll
                for (int t = 0; t < 8; t++)
                    af2[mt][t] = Pt[kc + q * 8 + t][cph];
            }
#pragma unroll
            for (int ot = 0; ot < 4; ot++)
                bf2[ot] = *(const half8*)&Wos[ot * 16 + l16][kc + q * 8];
#pragma unroll
            for (int mt = 0; mt < 2; mt++)
#pragma unroll
                for (int ot = 0; ot < 4; ot++)
                    u2acc[mt][ot] = __builtin_amdgcn_mfma_f32_16x16x32_f16(af2[mt], bf2[ot], u2acc[mt][ot], 0, 0, 0);
        }
        __syncthreads();
    }

    const float sc = 1.f / 4096.f;
    float* Ud = U2 + (long long)db * 262144;
#pragma unroll
    for (int mt = 0; mt < 2; mt++)
#pragma unroll
        for (int ot = 0; ot < 4; ot++)
#pragma unroll
            for (int t = 0; t < 4; t++) {
                int j = bp * 512 + ch0 + w * 32 + mt * 16 + q * 4 + t;
                Ud[(long long)j * 64 + ot * 16 + l16] = u2acc[mt][ot][t] * sc;
            }
}

// ---------------------------------------------------------------------------
// MFMA out:  out[db][n][o] = sum_{bp,c} emb_kv[bp][n][c] * ZstT[db][o][bp*64+c]
// A = emb (fp32 -> fp16 at LDS staging), B = ZstT fp16 [o][k].
// grid (16 n-tiles of 128, 16 db), block 256 (4 waves). K = 512 (8 bp x 64).
// ---------------------------------------------------------------------------
__global__ __launch_bounds__(256)
void mfma_out(const float* __restrict__ emb, const __half* __restrict__ ZstT,
              float* __restrict__ out)
{
    __shared__ __half Xs[128][72];
    __shared__ __half Bs[64][72];
    const int tid = threadIdx.x;
    const int db = blockIdx.y;
    const int d = db >> 3;
    const int n0 = blockIdx.x * 128;
    const float* Xb = emb + (long long)(1 - d) * 1048576;   // kv half
    const __half* Bz = ZstT + (long long)db * 32768;

    const int lane = tid & 63, w = tid >> 6, q = lane >> 4, l16 = lane & 15;

    float4v acc[2][4];
#pragma unroll
    for (int a = 0; a < 2; a++)
#pragma unroll
        for (int b = 0; b < 4; b++) acc[a][b] = (float4v)0.f;

    for (int bp = 0; bp < 8; bp++) {
        const float* src = Xb + (long long)bp * 131072 + (long long)n0 * 64;
#pragma unroll
        for (int it = 0; it < 8; it++) {
            int e = (tid + it * 256) * 4;
            int row = e >> 6, col = e & 63;
            float4 v = *(const float4*)(src + (long long)row * 64 + col);
            *(__half2*)&Xs[row][col]     = __floats2half2_rn(v.x, v.y);
            *(__half2*)&Xs[row][col + 2] = __floats2half2_rn(v.z, v.w);
        }
        {
            int o = tid >> 2, c8 = (tid & 3) * 16;
            *(half8*)&Bs[o][c8]     = *(const half8*)(Bz + o * 512 + bp * 64 + c8);
            *(half8*)&Bs[o][c8 + 8] = *(const half8*)(Bz + o * 512 + bp * 64 + c8 + 8);
        }
        __syncthreads();
#pragma unroll
        for (int kc = 0; kc < 64; kc += 32) {
            half8 af[2], bf[4];
#pragma unroll
            for (int mt = 0; mt < 2; mt++)
                af[mt] = *(const half8*)&Xs[w * 32 + mt * 16 + l16][kc + q * 8];
#pragma unroll
            for (int ot = 0; ot < 4; ot++)
                bf[ot] = *(const half8*)&Bs[ot * 16 + l16][kc + q * 8];
#pragma unroll
            for (int mt = 0; mt < 2; mt++)
#pragma unroll
                for (int ot = 0; ot < 4; ot++)
                    acc[mt][ot] = __builtin_amdgcn_mfma_f32_16x16x32_f16(af[mt], bf[ot], acc[mt][ot], 0, 0, 0);
        }
        __syncthreads();
    }

    float* Od = out + (long long)db * 131072;
#pragma unroll
    for (int mt = 0; mt < 2; mt++)
#pragma unroll
        for (int ot = 0; ot < 4; ot++)
#pragma unroll
            for (int t = 0; t < 4; t++) {
                int n = n0 + w * 32 + mt * 16 + q * 4 + t;
                Od[(long long)n * 64 + ot * 16 + l16] = acc[mt][ot][t];
            }
}

// ---------------------------------------------------------------------------
// Wo16T[z][o][i] = fp16(Wo[i][o] * 4096 / rs[z][i]).  grid 16, block 256.
// ---------------------------------------------------------------------------
__global__ __launch_bounds__(256)
void woprep_k(const float* __restrict__ Wo, const float* __restrict__ rs,
              __half* __restrict__ Wo16T)
{
    const int z = blockIdx.x;
    for (int idx = threadIdx.x; idx < 32768; idx += 256) {
        int o = idx >> 9, i = idx & 511;
        float v = Wo[i * 64 + o] * 4096.0f / rs[z * 512 + i];
        Wo16T[z * 32768 + idx] = __float2half(v);
    }
}

// ---------------------------------------------------------------------------
// Weight prep: transpose Wq/Wk/Wv (64x512 -> 512x64); also fp16 copy of WkT.
// ---------------------------------------------------------------------------
__global__ __launch_bounds__(256)
void wprep_k(const float* __restrict__ Wq, const float* __restrict__ Wk,
             const float* __restrict__ Wv, float* __restrict__ WqT,
             float* __restrict__ WkT, float* __restrict__ WvT,
             __half* __restrict__ WkT16)
{
    const int which = blockIdx.y;
    const float* in = which == 0 ? Wq : (which == 1 ? Wk : Wv);
    float* out      = which == 0 ? WqT : (which == 1 ? WkT : WvT);
    __shared__ float t[64][65];
    const int c0 = blockIdx.x * 64;
    const int c = threadIdx.x & 63, r4 = threadIdx.x >> 6;
#pragma unroll
    for (int rr = r4; rr < 64; rr += 4)
        t[rr][c] = in[rr * 512 + c0 + c];
    __syncthreads();
#pragma unroll
    for (int rr = r4; rr < 64; rr += 4) {
        float v = t[c][rr];
        out[(c0 + rr) * 64 + c] = v;
        if (which == 1) WkT16[(c0 + rr) * 64 + c] = __float2half(v);
    }
}

// ---------------------------------------------------------------------------
// Row sums of the 64x512 weight matrices.
// ---------------------------------------------------------------------------
__global__ __launch_bounds__(256)
void wsum_k(const float* __restrict__ Wq, const float* __restrict__ Wk,
            float* __restrict__ wqs, float* __restrict__ wks)
{
    const float* W = blockIdx.x ? Wk : Wq;
    float* o = blockIdx.x ? wks : wqs;
    __shared__ float acc[64];
    if (threadIdx.x < 64) acc[threadIdx.x] = 0.f;
    __syncthreads();
    for (int idx = threadIdx.x * 4; idx < 32768; idx += 1024) {
        float4 v = *(const float4*)(W + idx);
        atomicAdd(&acc[idx >> 9], v.x + v.y + v.z + v.w);
    }
    __syncthreads();
    if (threadIdx.x < 64) o[threadIdx.x] = acc[threadIdx.x];
}

// ---------------------------------------------------------------------------
// Analytic InstanceNorm stats from 64x64 Grams:
//   s1_pair = wqs^T G_pair wks ; s2_pair = <GQ*G_pair, G_pair*GW>
// ---------------------------------------------------------------------------
__global__ __launch_bounds__(256)
void stats2_k(const float* __restrict__ G, const float* __restrict__ GQ,
              const float* __restrict__ GW, const float* __restrict__ wqs,
              const float* __restrict__ wks, float* __restrict__ sums)
{
    __shared__ float Gs[64][68], GQs[64][68], GWs[64][68];
    const int tid = threadIdx.x;
    const float* Gp = G + (long long)blockIdx.x * 4096;
    for (int f = tid * 4; f < 4096; f += 1024) {
        int rr = f >> 6, cc = f & 63;
        *(float4*)&Gs[rr][cc]  = *(const float4*)(Gp + f);
        *(float4*)&GQs[rr][cc] = *(const float4*)(GQ + f);
        *(float4*)&GWs[rr][cc] = *(const float4*)(GW + f);
    }
    __syncthreads();
    const int r = tid >> 2;
    const int c0 = (tid & 3) * 16;
    float p1[16] = {}, p2[16] = {};
    for (int k = 0; k < 64; k++) {
        float gq = GQs[r][k], g = Gs[r][k];
#pragma unroll
        for (int j = 0; j < 16; j++) {
            p1[j] += gq * Gs[k][c0 + j];
            p2[j] += g  * GWs[k][c0 + j];
        }
    }
    float s2 = 0.f;
#pragma unroll
    for (int j = 0; j < 16; j++) s2 += p1[j] * p2[j];
    float s1 = 0.f;
    const float wq = wqs[r];
#pragma unroll
    for (int j = 0; j < 16; j++) s1 += wq * Gs[r][c0 + j] * wks[c0 + j];

    const int lane = tid & 63, w = tid >> 6;
#pragma unroll
    for (int off = 32; off; off >>= 1) {
        s1 += __shfl_down(s1, off, 64);
        s2 += __shfl_down(s2, off, 64);
    }
    __shared__ float r1[4], r2[4];
    if (lane == 0) { r1[w] = s1; r2[w] = s2; }
    __syncthreads();
    if (tid == 0) {
        atomicAdd(&sums[(blockIdx.x >> 3) * 2],     r1[0] + r1[1] + r1[2] + r1[3]);
        atomicAdd(&sums[(blockIdx.x >> 3) * 2 + 1], r2[0] + r2[1] + r2[2] + r2[3]);
    }
}

// ---------------------------------------------------------------------------
// Workspace (float offsets):
//   WkT @0:32768 | WqT @32768:32768 | WvT @65536:32768
//   zeroed block: G @98304:524288 | rs @622592:8192 | sums @630784:32
//                 GW @630816:4096 | GQ @634912:4096   (memset 540704)
//   wqs @639008:64 | wks @639072:64
//   E16 (half) @639136: 4194304 halves -> ends 2736288
//   Wo16T (half) @2736288: 524288 halves -> ends 2998432
//   WkT16 (half) @2998432: 32768 halves -> ends 3014816
//   U2 @3014816: 4194304 floats -> ends 7209120
//   ZstT (half) @7209120: 524288 halves -> ends 7471264
// ---------------------------------------------------------------------------
extern "C" void kernel_launch(void* const* d_in, const int* in_sizes, int n_in,
                              void* d_out, int out_size, void* d_ws, size_t ws_size,
                              hipStream_t stream)
{
    const float* emb = (const float*)d_in[0];
    const float* Wq  = (const float*)d_in[1];
    const float* Wk  = (const float*)d_in[2];
    const float* Wv  = (const float*)d_in[3];
    const float* Wo  = (const float*)d_in[4];
    float* out = (float*)d_out;
    float* ws  = (float*)d_ws;

    float* WkT   = ws;
    float* WqT   = ws + 32768;
    float* WvT   = ws + 65536;
    float* G     = ws + 98304;
    float* rs    = ws + 622592;
    float* sums  = ws + 630784;
    float* GW    = ws + 630816;
    float* GQ    = ws + 634912;
    float* wqs   = ws + 639008;
    float* wks   = ws + 639072;
    __half* E16   = (__half*)(ws + 639136);
    __half* Wo16T = (__half*)(ws + 2736288);
    __half* WkT16 = (__half*)(ws + 2998432);
    float* U2    = ws + 3014816;
    __half* ZstT  = (__half*)(ws + 7209120);

    wprep_k<<<dim3(8, 3), 256, 0, stream>>>(Wq, Wk, Wv, WqT, WkT, WvT, WkT16);
    hipMemsetAsync(G, 0, 540704 * sizeof(float), stream);     // G+rs+sums+GW+GQ
    wsum_k<<<2, 256, 0, stream>>>(Wq, Wk, wqs, wks);

    // G[z=(d*8+b)*8+b'] = emb_q[d,b]^T @ emb_kv[d,b']   K=2048 split-K16
    gemm_tn<64, 64, 16, 4, 4, 16, float, float><<<dim3(1, 16, 128), 256, 0, stream>>>(
        emb, emb + 1048576, G, 2048, 64, 64, 64,
        8, 131072LL, 1, 0LL,
        64, -1048576LL, 8, 131072LL,
        1, 4096LL, 1, 0LL);

    // GW (z=0 from WkT) and GQ (z=1 from WqT): 64x64, K=512, split-K8 batched
    gemm_tn<64, 64, 16, 4, 4, 8, float, float><<<dim3(1, 8, 2), 256, 0, stream>>>(
        WkT, WkT, GW, 512, 64, 64, 64,
        1, 0LL, 2, 32768LL,
        1, 0LL, 2, 32768LL,
        1, 0LL, 2, 4096LL);

    stats2_k<<<128, 256, 0, stream>>>(G, GQ, GW, wqs, wks, sums);

    // E16[pair][i][c'] = sum_c Wq[c][i] * G[pair][c][c']   (fp16 out)
    gemm_tn<64, 64, 16, 4, 4, 1, float, __half><<<dim3(1, 8, 128), 256, 0, stream>>>(
        Wq, G, E16, 64, 512, 64, 64,
        1, 0LL, 1, 0LL,
        1, 4096LL, 1, 0LL,
        1, 32768LL, 1, 0LL);

    // rs[db][i] = sum_j exp(r * S[i][j])   (MFMA, no S store)
    mfma_rows<<<dim3(4, 4, 128), 256, 0, stream>>>(E16, WkT16, sums, rs);

    // Wo16T[db][o][i] = fp16(Wo[i][o]*4096/rs[db][i])
    woprep_k<<<16, 256, 0, stream>>>(Wo, rs, Wo16T);

    // U2[db][j][o] = (1/4096) sum_i exp(r*S[i][j]) * Wo16T[o][i]  (fused)
    mfma_su2<<<dim3(32, 16), 256, 0, stream>>>(E16, WkT16, Wo16T, sums, U2);

    // ZstT[db][o][bp*64+c] = Z^T: sum_ch U2[db][bp*512+ch][o] * WvT[ch][c]
    gemm_tn<64, 64, 16, 4, 4, 1, float, __half><<<dim3(1, 1, 128), 256, 0, stream>>>(
        U2, WvT, ZstT, 512, 64, 64, 512,
        8, 262144LL, 8, 32768LL,
        1, 0LL, 1, 0LL,
        8, 32768LL, 8, 64LL);

    // out[db][n][o] = sum_k emb_kv * ZstT   (MFMA f16, fp32 out)
    mfma_out<<<dim3(16, 16), 256, 0, stream>>>(emb, ZstT, out);
}

// Round 10
// 224.050 us; speedup vs baseline: 1.5763x; 1.3639x over previous
//
#include <hip/hip_runtime.h>
#include <hip/hip_fp16.h>

#define EPS 1e-5f

typedef __attribute__((ext_vector_type(8))) _Float16 half8;
typedef __attribute__((ext_vector_type(4))) float float4v;

// ---------------------------------------------------------------------------
// Generalized batched TN GEMM: C[m][n] = sum_k A[k][m] * B[k][n]
// Offsets per z:  off = (z/div)*bsd + (z%mod)*bsm  (element units)
// KS>1: split-K, atomicAdd into pre-zeroed C (small outputs only!).
// TC=__half: scalar converting stores (KS==1 only).
// ---------------------------------------------------------------------------
template<int BM, int BN, int BK, int TM, int TN, int KS, typename TA, typename TC>
__global__ __launch_bounds__((BM/TM)*(BN/TN))
void gemm_tn(const TA* __restrict__ A, const float* __restrict__ B,
             TC* __restrict__ C, int K,
             int lda, int ldb, int ldc,
             int divA, long long bsAd, int modA, long long bsAm,
             int divB, long long bsBd, int modB, long long bsBm,
             int divC, long long bsCd, int modC, long long bsCm)
{
    constexpr int T  = (BM/TM)*(BN/TN);
    constexpr int HM = TM/2, HN = TN/2;
    __shared__ float As[BK][BM];
    __shared__ float Bs[BK][BN];

    const int tid = threadIdx.x;
    const int z = blockIdx.z;
    const int mtile = blockIdx.y / KS;
    const int ks = blockIdx.y % KS;
    const int n0 = blockIdx.x * BN;
    const int m0 = mtile * BM;
    A += (long long)(z / divA) * bsAd + (long long)(z % modA) * bsAm;
    B += (long long)(z / divB) * bsBd + (long long)(z % modB) * bsBm;
    C += (long long)(z / divC) * bsCd + (long long)(z % modC) * bsCm;

    const int tx = tid % (BN/TN);
    const int ty = tid / (BN/TN);

    float acc[TM][TN] = {};

    const int kc = K / KS;
    const int kBeg = ks * kc;

    for (int k0 = kBeg; k0 < kBeg + kc; k0 += BK) {
#pragma unroll
        for (int idx = tid * 4; idx < BK * BM; idx += T * 4) {
            int rr = idx / BM, cc = idx % BM;
            *(float4*)&As[rr][cc] = *(const float4*)(A + (long long)(k0 + rr) * lda + m0 + cc);
        }
#pragma unroll
        for (int idx = tid * 4; idx < BK * BN; idx += T * 4) {
            int rr = idx / BN, cc = idx % BN;
            *(float4*)&Bs[rr][cc] = *(const float4*)(B + (long long)(k0 + rr) * ldb + n0 + cc);
        }
        __syncthreads();
#pragma unroll
        for (int kk = 0; kk < BK; kk++) {
            float a[TM], b[TN];
#pragma unroll
            for (int u = 0; u < HM; u++) {
                a[u]      = As[kk][ty * HM + u];
                a[HM + u] = As[kk][BM / 2 + ty * HM + u];
            }
#pragma unroll
            for (int v = 0; v < HN; v++) {
                b[v]      = Bs[kk][tx * HN + v];
                b[HN + v] = Bs[kk][BN / 2 + tx * HN + v];
            }
#pragma unroll
            for (int u = 0; u < TM; u++)
#pragma unroll
                for (int v = 0; v < TN; v++)
                    acc[u][v] += a[u] * b[v];
        }
        __syncthreads();
    }

    if constexpr (KS > 1) {
#pragma unroll
        for (int u = 0; u < TM; u++) {
            int rl = (u < HM) ? ty * HM + u : BM / 2 + ty * HM + (u - HM);
#pragma unroll
            for (int v = 0; v < TN; v++) {
                int cl = (v < HN) ? tx * HN + v : BN / 2 + tx * HN + (v - HN);
                atomicAdd(&C[(long long)(m0 + rl) * ldc + n0 + cl], acc[u][v]);
            }
        }
    } else {
#pragma unroll
        for (int u = 0; u < TM; u++) {
            int rl = (u < HM) ? ty * HM + u : BM / 2 + ty * HM + (u - HM);
            TC* cr = C + (long long)(m0 + rl) * ldc + n0;
            if constexpr (sizeof(TC) == 2) {
#pragma unroll
                for (int v = 0; v < HN; v++) {
                    cr[tx * HN + v]          = __float2half(acc[u][v]);
                    cr[BN / 2 + tx * HN + v] = __float2half(acc[u][HN + v]);
                }
            } else if constexpr (HN == 4) {
                *(float4*)(cr + tx * HN) = make_float4(acc[u][0], acc[u][1], acc[u][2], acc[u][3]);
                *(float4*)(cr + BN / 2 + tx * HN) = make_float4(acc[u][4], acc[u][5], acc[u][6], acc[u][7]);
            } else {
#pragma unroll
                for (int v = 0; v < HN; v++) {
                    cr[tx * HN + v] = acc[u][v];
                    cr[BN / 2 + tx * HN + v] = acc[u][HN + v];
                }
            }
        }
    }
}

// ---------------------------------------------------------------------------
// MFMA Gram: Gpart[ks][z][c][c'] = sum_{tok in ks-slice} Xq[tok][c]*Xkv[tok][c']
// emb fp32 -> fp16 transposed at LDS staging. Plain stores (no atomics);
// the 8 partials are reduced inside stats2_k. grid (8 ks, 128 pairs).
// ---------------------------------------------------------------------------
__global__ __launch_bounds__(256)
void mfma_G(const float* __restrict__ emb, float* __restrict__ Gpart)
{
    __shared__ __half As[64][72];
    __shared__ __half Bs[64][72];
    const int tid = threadIdx.x;
    const int ks = blockIdx.x;
    const int z  = blockIdx.y;               // pair = (d*8+b)*8+b'
    const int d  = z >> 6;
    const int bp = z & 7;
    const float* Xq  = emb + (long long)(z >> 3) * 131072;
    const float* Xkv = emb + (long long)(1 - d) * 1048576 + (long long)bp * 131072;

    const int lane = tid & 63, w = tid >> 6, q = lane >> 4, l16 = lane & 15;
    const int tok = tid & 63;
    const int cg  = w * 16;

    float4v acc[4];
#pragma unroll
    for (int nt = 0; nt < 4; nt++) acc[nt] = (float4v)0.f;

    for (int t0 = ks * 256; t0 < ks * 256 + 256; t0 += 64) {
        const float* q4 = Xq  + (long long)(t0 + tok) * 64 + cg;
        const float* k4 = Xkv + (long long)(t0 + tok) * 64 + cg;
#pragma unroll
        for (int j = 0; j < 4; j++) {
            float4 v = *(const float4*)(q4 + j * 4);
            As[cg + j * 4 + 0][tok] = __float2half(v.x);
            As[cg + j * 4 + 1][tok] = __float2half(v.y);
            As[cg + j * 4 + 2][tok] = __float2half(v.z);
            As[cg + j * 4 + 3][tok] = __float2half(v.w);
            float4 u = *(const float4*)(k4 + j * 4);
            Bs[cg + j * 4 + 0][tok] = __float2half(u.x);
            Bs[cg + j * 4 + 1][tok] = __float2half(u.y);
            Bs[cg + j * 4 + 2][tok] = __float2half(u.z);
            Bs[cg + j * 4 + 3][tok] = __float2half(u.w);
        }
        __syncthreads();
#pragma unroll
        for (int kc = 0; kc < 64; kc += 32) {
            half8 af = *(const half8*)&As[w * 16 + l16][kc + q * 8];
            half8 bf[4];
#pragma unroll
            for (int nt = 0; nt < 4; nt++)
                bf[nt] = *(const half8*)&Bs[nt * 16 + l16][kc + q * 8];
#pragma unroll
            for (int nt = 0; nt < 4; nt++)
                acc[nt] = __builtin_amdgcn_mfma_f32_16x16x32_f16(af, bf[nt], acc[nt], 0, 0, 0);
        }
        __syncthreads();
    }

    float* Gz = Gpart + (long long)ks * 524288 + (long long)z * 4096;
#pragma unroll
    for (int nt = 0; nt < 4; nt++)
#pragma unroll
        for (int t = 0; t < 4; t++) {
            int m = w * 16 + q * 4 + t;
            Gz[m * 64 + nt * 16 + l16] = acc[nt][t];
        }
}

// ---------------------------------------------------------------------------
// MFMA rowsums:  rs[db][i] += sum_ch exp(r * S[i][ch-tile])  (no S store).
// ---------------------------------------------------------------------------
__global__ __launch_bounds__(256)
void mfma_rows(const __half* __restrict__ E16, const __half* __restrict__ WkT16,
               const float* __restrict__ sums, float* __restrict__ rs)
{
    __shared__ __half Es[128][72];
    __shared__ __half Ws[128][72];
    const int tid = threadIdx.x;
    const int z = blockIdx.z;          // pair = db*8 + b'
    const int i0 = blockIdx.y * 128;
    const int ch0 = blockIdx.x * 128;
    const int db = z >> 3;
    const __half* Ez = E16 + (long long)z * 32768;

#pragma unroll
    for (int it = 0; it < 4; it++) {
        int e = tid + it * 256;
        int row = e >> 3, c8 = (e & 7) * 8;
        *(half8*)&Es[row][c8] = *(const half8*)(Ez + (long long)(i0 + row) * 64 + c8);
        *(half8*)&Ws[row][c8] = *(const half8*)(WkT16 + (long long)(ch0 + row) * 64 + c8);
    }
    __syncthreads();

    const int lane = tid & 63;
    const int w = tid >> 6;
    const int q = lane >> 4;
    const int l16 = lane & 15;

    float4v acc[2][8];
#pragma unroll
    for (int a = 0; a < 2; a++)
#pragma unroll
        for (int b = 0; b < 8; b++) acc[a][b] = (float4v)0.f;

#pragma unroll
    for (int kc = 0; kc < 64; kc += 32) {
        half8 af[2], bf[8];
#pragma unroll
        for (int mt = 0; mt < 2; mt++)
            af[mt] = *(const half8*)&Es[w * 32 + mt * 16 + l16][kc + q * 8];
#pragma unroll
        for (int nt = 0; nt < 8; nt++)
            bf[nt] = *(const half8*)&Ws[nt * 16 + l16][kc + q * 8];
#pragma unroll
        for (int mt = 0; mt < 2; mt++)
#pragma unroll
            for (int nt = 0; nt < 8; nt++)
                acc[mt][nt] = __builtin_amdgcn_mfma_f32_16x16x32_f16(af[mt], bf[nt], acc[mt][nt], 0, 0, 0);
    }

    const float inv = 1.f / 2097152.f;
    const float mu  = sums[2 * db] * inv;
    const float var = sums[2 * db + 1] * inv - mu * mu;
    const float rv  = rsqrtf(var + EPS);

    float* rsb = rs + db * 512 + i0 + w * 32;
#pragma unroll
    for (int mt = 0; mt < 2; mt++) {
#pragma unroll
        for (int t = 0; t < 4; t++) {
            const int irow = mt * 16 + q * 4 + t;
            float p = 0.f;
#pragma unroll
            for (int nt = 0; nt < 8; nt++) p += __expf(rv * acc[mt][nt][t]);
            p += __shfl_xor(p, 1, 16);
            p += __shfl_xor(p, 2, 16);
            p += __shfl_xor(p, 4, 16);
            p += __shfl_xor(p, 8, 16);
            if (l16 == 0) atomicAdd(&rsb[irow], p);
        }
    }
}

// ---------------------------------------------------------------------------
// Fused S-recompute + exp(+softmax-normalize) + U2 contraction.
// Pt = fp16(4096 * exp(rv*s) / rs[i]); Wo16 db-independent fp16(Wo^T).
// ---------------------------------------------------------------------------
__global__ __launch_bounds__(256)
void mfma_su2(const __half* __restrict__ E16, const __half* __restrict__ WkT16,
              const __half* __restrict__ Wo16, const float* __restrict__ rs,
              const float* __restrict__ sums, float* __restrict__ U2)
{
    __shared__ __half Ws[128][72];
    __shared__ __half Es[64][72];
    __shared__ __half Wos[64][72];
    __shared__ __half Pt[64][136];
    __shared__ float rsS[64];

    const int tid = threadIdx.x;
    const int jt = blockIdx.x;
    const int db = blockIdx.y;
    const int bp = jt >> 2;
    const int ch0 = (jt & 3) * 128;
    const int z = db * 8 + bp;

    const __half* Ez = E16 + (long long)z * 32768;

#pragma unroll
    for (int it = 0; it < 4; it++) {
        int e = tid + it * 256;
        int row = e >> 3, c8 = (e & 7) * 8;
        *(half8*)&Ws[row][c8] = *(const half8*)(WkT16 + (long long)(ch0 + row) * 64 + c8);
    }

    const int lane = tid & 63;
    const int w = tid >> 6;
    const int q = lane >> 4;
    const int l16 = lane & 15;

    const float inv = 1.f / 2097152.f;
    const float mu  = sums[2 * db] * inv;
    const float var = sums[2 * db + 1] * inv - mu * mu;
    const float rv  = rsqrtf(var + EPS);

    float4v u2acc[2][4];
#pragma unroll
    for (int a = 0; a < 2; a++)
#pragma unroll
        for (int b = 0; b < 4; b++) u2acc[a][b] = (float4v)0.f;

    const int lrow = tid >> 2;
    const int lc8 = (tid & 3) * 16;

    for (int i0 = 0; i0 < 512; i0 += 64) {
        *(half8*)&Es[lrow][lc8]      = *(const half8*)(Ez + (long long)(i0 + lrow) * 64 + lc8);
        *(half8*)&Es[lrow][lc8 + 8]  = *(const half8*)(Ez + (long long)(i0 + lrow) * 64 + lc8 + 8);
        *(half8*)&Wos[lrow][lc8]     = *(const half8*)(Wo16 + (long long)lrow * 512 + i0 + lc8);
        *(half8*)&Wos[lrow][lc8 + 8] = *(const half8*)(Wo16 + (long long)lrow * 512 + i0 + lc8 + 8);
        if (tid < 64) rsS[tid] = rs[db * 512 + i0 + tid];
        __syncthreads();

        float4v sacc[2][4];
#pragma unroll
        for (int a = 0; a < 2; a++)
#pragma unroll
            for (int b = 0; b < 4; b++) sacc[a][b] = (float4v)0.f;
#pragma unroll
        for (int kc = 0; kc < 64; kc += 32) {
            half8 af[2], bf[4];
#pragma unroll
            for (int ct = 0; ct < 2; ct++)
                af[ct] = *(const half8*)&Ws[w * 32 + ct * 16 + l16][kc + q * 8];
#pragma unroll
            for (int it = 0; it < 4; it++)
                bf[it] = *(const half8*)&Es[it * 16 + l16][kc + q * 8];
#pragma unroll
            for (int ct = 0; ct < 2; ct++)
#pragma unroll
                for (int it = 0; it < 4; it++)
                    sacc[ct][it] = __builtin_amdgcn_mfma_f32_16x16x32_f16(af[ct], bf[it], sacc[ct][it], 0, 0, 0);
        }

        float invr[4];
#pragma unroll
        for (int it = 0; it < 4; it++) invr[it] = 4096.0f / rsS[it * 16 + l16];

#pragma unroll
        for (int ct = 0; ct < 2; ct++)
#pragma unroll
            for (int it = 0; it < 4; it++) {
                float e0 = __expf(rv * sacc[ct][it][0]) * invr[it];
                float e1 = __expf(rv * sacc[ct][it][1]) * invr[it];
                float e2 = __expf(rv * sacc[ct][it][2]) * invr[it];
                float e3 = __expf(rv * sacc[ct][it][3]) * invr[it];
                int row = it * 16 + l16;
                int swz = ((row >> 3) & 3) << 4;
                int col = (w * 32 + ct * 16 + q * 4) ^ swz;
                *(__half2*)&Pt[row][col]     = __floats2half2_rn(e0, e1);
                *(__half2*)&Pt[row][col + 2] = __floats2half2_rn(e2, e3);
            }
        __syncthreads();

#pragma unroll
        for (int kc = 0; kc < 64; kc += 32) {
            half8 af2[2], bf2[4];
#pragma unroll
            for (int mt = 0; mt < 2; mt++) {
                const int cph = (w * 32 + mt * 16 + l16) ^ (q << 4);
#pragma unroll
                for (int t = 0; t < 8; t++)
                    af2[mt][t] = Pt[kc + q * 8 + t][cph];
            }
#pragma unroll
            for (int ot = 0; ot < 4; ot++)
                bf2[ot] = *(const half8*)&Wos[ot * 16 + l16][kc + q * 8];
#pragma unroll
            for (int mt = 0; mt < 2; mt++)
#pragma unroll
                for (int ot = 0; ot < 4; ot++)
                    u2acc[mt][ot] = __builtin_amdgcn_mfma_f32_16x16x32_f16(af2[mt], bf2[ot], u2acc[mt][ot], 0, 0, 0);
        }
        __syncthreads();
    }

    const float sc = 1.f / 4096.f;
    float* Ud = U2 + (long long)db * 262144;
#pragma unroll
    for (int mt = 0; mt < 2; mt++)
#pragma unroll
        for (int ot = 0; ot < 4; ot++)
#pragma unroll
            for (int t = 0; t < 4; t++) {
                int j = bp * 512 + ch0 + w * 32 + mt * 16 + q * 4 + t;
                Ud[(long long)j * 64 + ot * 16 + l16] = u2acc[mt][ot][t] * sc;
            }
}

// ---------------------------------------------------------------------------
// MFMA out:  out[db][n][o] = sum_{bp,c} emb_kv[bp][n][c] * ZstT[db][o][bp*64+c]
// ---------------------------------------------------------------------------
__global__ __launch_bounds__(256)
void mfma_out(const float* __restrict__ emb, const __half* __restrict__ ZstT,
              float* __restrict__ out)
{
    __shared__ __half Xs[128][72];
    __shared__ __half Bs[64][72];
    const int tid = threadIdx.x;
    const int db = blockIdx.y;
    const int d = db >> 3;
    const int n0 = blockIdx.x * 128;
    const float* Xb = emb + (long long)(1 - d) * 1048576;
    const __half* Bz = ZstT + (long long)db * 32768;

    const int lane = tid & 63, w = tid >> 6, q = lane >> 4, l16 = lane & 15;

    float4v acc[2][4];
#pragma unroll
    for (int a = 0; a < 2; a++)
#pragma unroll
        for (int b = 0; b < 4; b++) acc[a][b] = (float4v)0.f;

    for (int bp = 0; bp < 8; bp++) {
        const float* src = Xb + (long long)bp * 131072 + (long long)n0 * 64;
#pragma unroll
        for (int it = 0; it < 8; it++) {
            int e = (tid + it * 256) * 4;
            int row = e >> 6, col = e & 63;
            float4 v = *(const float4*)(src + (long long)row * 64 + col);
            *(__half2*)&Xs[row][col]     = __floats2half2_rn(v.x, v.y);
            *(__half2*)&Xs[row][col + 2] = __floats2half2_rn(v.z, v.w);
        }
        {
            int o = tid >> 2, c8 = (tid & 3) * 16;
            *(half8*)&Bs[o][c8]     = *(const half8*)(Bz + o * 512 + bp * 64 + c8);
            *(half8*)&Bs[o][c8 + 8] = *(const half8*)(Bz + o * 512 + bp * 64 + c8 + 8);
        }
        __syncthreads();
#pragma unroll
        for (int kc = 0; kc < 64; kc += 32) {
            half8 af[2], bf[4];
#pragma unroll
            for (int mt = 0; mt < 2; mt++)
                af[mt] = *(const half8*)&Xs[w * 32 + mt * 16 + l16][kc + q * 8];
#pragma unroll
            for (int ot = 0; ot < 4; ot++)
                bf[ot] = *(const half8*)&Bs[ot * 16 + l16][kc + q * 8];
#pragma unroll
            for (int mt = 0; mt < 2; mt++)
#pragma unroll
                for (int ot = 0; ot < 4; ot++)
                    acc[mt][ot] = __builtin_amdgcn_mfma_f32_16x16x32_f16(af[mt], bf[ot], acc[mt][ot], 0, 0, 0);
        }
        __syncthreads();
    }

    float* Od = out + (long long)db * 131072;
#pragma unroll
    for (int mt = 0; mt < 2; mt++)
#pragma unroll
        for (int ot = 0; ot < 4; ot++)
#pragma unroll
            for (int t = 0; t < 4; t++) {
                int n = n0 + w * 32 + mt * 16 + q * 4 + t;
                Od[(long long)n * 64 + ot * 16 + l16] = acc[mt][ot][t];
            }
}

// ---------------------------------------------------------------------------
// Weight prep: y=0..2 transpose Wq/Wk/Wv (64x512 -> 512x64), fp16 WkT, and
// row-sum atomics into wqs/wks (pre-zeroed); y=3 builds Wo16[o][i]=fp16(Wo[i][o]).
// grid (8, 4), block 256.
// ---------------------------------------------------------------------------
__global__ __launch_bounds__(256)
void wprep_k(const float* __restrict__ Wq, const float* __restrict__ Wk,
             const float* __restrict__ Wv, const float* __restrict__ Wo,
             float* __restrict__ WqT, float* __restrict__ WkT,
             float* __restrict__ WvT, __half* __restrict__ WkT16,
             __half* __restrict__ Wo16, float* __restrict__ wqs,
             float* __restrict__ wks)
{
    const int which = blockIdx.y;
    __shared__ float t[64][65];
    const int c0 = blockIdx.x * 64;
    const int c = threadIdx.x & 63, r4 = threadIdx.x >> 6;

    if (which < 3) {
        const float* in = which == 0 ? Wq : (which == 1 ? Wk : Wv);
        float* out      = which == 0 ? WqT : (which == 1 ? WkT : WvT);
#pragma unroll
        for (int rr = r4; rr < 64; rr += 4)
            t[rr][c] = in[rr * 512 + c0 + c];
        __syncthreads();
#pragma unroll
        for (int rr = r4; rr < 64; rr += 4) {
            float v = t[c][rr];
            out[(c0 + rr) * 64 + c] = v;
            if (which == 1) WkT16[(c0 + rr) * 64 + c] = __float2half(v);
        }
        if (which < 2 && threadIdx.x < 64) {
            float s = 0.f;
#pragma unroll
            for (int j = 0; j < 64; j++) s += t[threadIdx.x][j];
            atomicAdd((which == 0 ? wqs : wks) + threadIdx.x, s);
        }
    } else {
        // Wo [512][64] -> Wo16[o][i] fp16
#pragma unroll
        for (int rr = r4; rr < 64; rr += 4)
            t[rr][c] = Wo[(c0 + rr) * 64 + c];
        __syncthreads();
#pragma unroll
        for (int rr = r4; rr < 64; rr += 4)
            Wo16[rr * 512 + c0 + c] = __float2half(t[c][rr]);
    }
}

// ---------------------------------------------------------------------------
// Analytic InstanceNorm stats from 64x64 Grams + 8-way split-K reduce of
// Gpart (writes reduced G back into slice 0 for the E16 gemm):
//   s1_pair = wqs^T G_pair wks ; s2_pair = <GQ*G_pair, G_pair*GW>
// ---------------------------------------------------------------------------
__global__ __launch_bounds__(256)
void stats2_k(float* __restrict__ Gpart, const float* __restrict__ GQ,
              const float* __restrict__ GW, const float* __restrict__ wqs,
              const float* __restrict__ wks, float* __restrict__ sums)
{
    __shared__ float Gs[64][68], GQs[64][68], GWs[64][68];
    const int tid = threadIdx.x;
    const int z = blockIdx.x;
    for (int f = tid * 4; f < 4096; f += 1024) {
        float4 g = make_float4(0.f, 0.f, 0.f, 0.f);
#pragma unroll
        for (int s = 0; s < 8; s++) {
            float4 p = *(const float4*)(Gpart + (long long)s * 524288 + (long long)z * 4096 + f);
            g.x += p.x; g.y += p.y; g.z += p.z; g.w += p.w;
        }
        *(float4*)(Gpart + (long long)z * 4096 + f) = g;   // reduced G (slice 0)
        int rr = f >> 6, cc = f & 63;
        *(float4*)&Gs[rr][cc]  = g;
        *(float4*)&GQs[rr][cc] = *(const float4*)(GQ + f);
        *(float4*)&GWs[rr][cc] = *(const float4*)(GW + f);
    }
    __syncthreads();
    const int r = tid >> 2;
    const int c0 = (tid & 3) * 16;
    float p1[16] = {}, p2[16] = {};
    for (int k = 0; k < 64; k++) {
        float gq = GQs[r][k], g = Gs[r][k];
#pragma unroll
        for (int j = 0; j < 16; j++) {
            p1[j] += gq * Gs[k][c0 + j];
            p2[j] += g  * GWs[k][c0 + j];
        }
    }
    float s2 = 0.f;
#pragma unroll
    for (int j = 0; j < 16; j++) s2 += p1[j] * p2[j];
    float s1 = 0.f;
    const float wq = wqs[r];
#pragma unroll
    for (int j = 0; j < 16; j++) s1 += wq * Gs[r][c0 + j] * wks[c0 + j];

    const int lane = tid & 63, w = tid >> 6;
#pragma unroll
    for (int off = 32; off; off >>= 1) {
        s1 += __shfl_down(s1, off, 64);
        s2 += __shfl_down(s2, off, 64);
    }
    __shared__ float r1[4], r2[4];
    if (lane == 0) { r1[w] = s1; r2[w] = s2; }
    __syncthreads();
    if (tid == 0) {
        atomicAdd(&sums[(blockIdx.x >> 3) * 2],     r1[0] + r1[1] + r1[2] + r1[3]);
        atomicAdd(&sums[(blockIdx.x >> 3) * 2 + 1], r2[0] + r2[1] + r2[2] + r2[3]);
    }
}

// ---------------------------------------------------------------------------
// Workspace (float offsets):
//   WkT @0:32768 | WqT @32768:32768 | WvT @65536:32768
//   zeroed @98304: rs 8192 | sums @106496:32 | GW @106528:4096 | GQ @110624:4096
//                  wqs @114720:64 | wks @114784:64   (memset 16544 floats)
//   Gpart @114848: 8 x 524288 = 4194304 (slice 0 becomes reduced G)
//   E16 (half) @4309152: 4194304 halves -> ends 6406304
//   WkT16 (half) @6406304: 32768 halves -> ends 6422688
//   Wo16 (half) @6422688: 32768 halves -> ends 6439072
//   U2 @6439072: 4194304 floats -> ends 10633376
//   ZstT (half) @10633376: 524288 halves -> ends 10895520
// ---------------------------------------------------------------------------
extern "C" void kernel_launch(void* const* d_in, const int* in_sizes, int n_in,
                              void* d_out, int out_size, void* d_ws, size_t ws_size,
                              hipStream_t stream)
{
    const float* emb = (const float*)d_in[0];
    const float* Wq  = (const float*)d_in[1];
    const float* Wk  = (const float*)d_in[2];
    const float* Wv  = (const float*)d_in[3];
    const float* Wo  = (const float*)d_in[4];
    float* out = (float*)d_out;
    float* ws  = (float*)d_ws;

    float* WkT   = ws;
    float* WqT   = ws + 32768;
    float* WvT   = ws + 65536;
    float* zero0 = ws + 98304;
    float* rs    = ws + 98304;
    float* sums  = ws + 106496;
    float* GW    = ws + 106528;
    float* GQ    = ws + 110624;
    float* wqs   = ws + 114720;
    float* wks   = ws + 114784;
    float* Gpart = ws + 114848;
    __half* E16   = (__half*)(ws + 4309152);
    __half* WkT16 = (__half*)(ws + 6406304);
    __half* Wo16  = (__half*)(ws + 6422688);
    float* U2    = ws + 6439072;
    __half* ZstT  = (__half*)(ws + 10633376);

    hipMemsetAsync(zero0, 0, 16544 * sizeof(float), stream);  // rs+sums+GW+GQ+wqs+wks
    wprep_k<<<dim3(8, 4), 256, 0, stream>>>(Wq, Wk, Wv, Wo, WqT, WkT, WvT,
                                            WkT16, Wo16, wqs, wks);

    // Gpart[ks][pair] = partial Gram (MFMA fp16, plain stores)
    mfma_G<<<dim3(8, 128), 256, 0, stream>>>(emb, Gpart);

    // GW (z=0 from WkT) and GQ (z=1 from WqT): 64x64, K=512, split-K8 batched
    gemm_tn<64, 64, 16, 4, 4, 8, float, float><<<dim3(1, 8, 2), 256, 0, stream>>>(
        WkT, WkT, GW, 512, 64, 64, 64,
        1, 0LL, 2, 32768LL,
        1, 0LL, 2, 32768LL,
        1, 0LL, 2, 4096LL);

    // reduce Gpart 8->1 + analytic IN stats
    stats2_k<<<128, 256, 0, stream>>>(Gpart, GQ, GW, wqs, wks, sums);

    // E16[pair][i][c'] = sum_c Wq[c][i] * G[pair][c][c']   (fp16 out)
    gemm_tn<64, 64, 16, 4, 4, 1, float, __half><<<dim3(1, 8, 128), 256, 0, stream>>>(
        Wq, Gpart, E16, 64, 512, 64, 64,
        1, 0LL, 1, 0LL,
        1, 4096LL, 1, 0LL,
        1, 32768LL, 1, 0LL);

    // rs[db][i] = sum_j exp(r * S[i][j])   (MFMA, no S store)
    mfma_rows<<<dim3(4, 4, 128), 256, 0, stream>>>(E16, WkT16, sums, rs);

    // U2[db][j][o] = sum_i attn[i][j] * Wo[i][o]   (fused recompute, MFMA)
    mfma_su2<<<dim3(32, 16), 256, 0, stream>>>(E16, WkT16, Wo16, rs, sums, U2);

    // ZstT[db][o][bp*64+c] = sum_ch U2[db][bp*512+ch][o] * WvT[ch][c]
    gemm_tn<64, 64, 16, 4, 4, 1, float, __half><<<dim3(1, 1, 128), 256, 0, stream>>>(
        U2, WvT, ZstT, 512, 64, 64, 512,
        8, 262144LL, 8, 32768LL,
        1, 0LL, 1, 0LL,
        8, 32768LL, 8, 64LL);

    // out[db][n][o] = sum_k emb_kv * ZstT   (MFMA f16, fp32 out)
    mfma_out<<<dim3(16, 16), 256, 0, stream>>>(emb, ZstT, out);
}